// Round 13
// baseline (694.281 us; speedup 1.0000x reference)
//
#include <hip/hip_runtime.h>
#include <cstdint>
#include <cstddef>

#define BB 128
#define NN 1024
#define NI 64
#define TT 512
#define MAXNNZ 16384
#define NE 28
#define TH 16

// ws layout (bytes)
#define WS_OFFS   0u         // int[1025]
#define WS_CNT    8192u      // int[1024]
#define WS_IDX    16384u     // u16[MAXNNZ]
#define WS_VAL    65536u     // f32[MAXNNZ]
#define WS_PERM   131072u    // int[1024]
#define WS_IPERM  135168u    // int[1024]
#define WS_XSTATE 139264u    // f32[BB*NN]
#define WS_WINP   663552u    // f32[NI*NN]
#define WS_EIDX2  925696u    // u16[NE*NN] = 57344
#define WS_CNT16  983040u    // int[1024*16] = 65536
#define WS_OFF16  1048576u   // int[1024*16] = 65536
#define WS_U      1114112u   // f32 U chunk [Tc][BB][NN]

// ---------- sparse build (parallel, deterministic k-order) ----------
__global__ __launch_bounds__(64) void k_count16(const float* __restrict__ W, int* __restrict__ cnt16) {
    int bc = blockIdx.x;
    int s = bc & 15, g = bc >> 4;
    int col = g * 64 + threadIdx.x;
    int c = 0;
    for (int q = 0; q < 64; ++q) {
        int k = s * 64 + q;
        c += (W[(size_t)k * NN + col] != 0.0f) ? 1 : 0;
    }
    cnt16[col * 16 + s] = c;
}

__global__ __launch_bounds__(1024) void k_sum16(const int* __restrict__ cnt16, int* __restrict__ cnt) {
    int col = threadIdx.x;
    int t = 0;
#pragma unroll
    for (int s = 0; s < 16; ++s) t += cnt16[col * 16 + s];
    cnt[col] = t;
}

__global__ __launch_bounds__(1024) void k_scan(const int* __restrict__ cnt, int* __restrict__ offs) {
    __shared__ int s[NN];
    int tid = threadIdx.x;
    s[tid] = cnt[tid];
    __syncthreads();
    for (int d = 1; d < NN; d <<= 1) {
        int v = (tid >= d) ? s[tid - d] : 0;
        __syncthreads();
        s[tid] += v;
        __syncthreads();
    }
    int incl = s[tid];
    offs[tid + 1] = (incl < MAXNNZ) ? incl : MAXNNZ;
    if (tid == 0) offs[0] = 0;
}

__global__ __launch_bounds__(1024) void k_off16(const int* __restrict__ offs, const int* __restrict__ cnt16,
                                                int* __restrict__ off16) {
    int col = threadIdx.x;
    int base = offs[col];
#pragma unroll
    for (int s = 0; s < 16; ++s) {
        off16[col * 16 + s] = base;
        base += cnt16[col * 16 + s];
    }
}

__global__ __launch_bounds__(64) void k_fill16(const float* __restrict__ W, const int* __restrict__ off16,
                                               unsigned short* __restrict__ idx, float* __restrict__ val) {
    int bc = blockIdx.x;
    int s = bc & 15, g = bc >> 4;
    int col = g * 64 + threadIdx.x;
    int p = off16[col * 16 + s];
    for (int q = 0; q < 64; ++q) {
        int k = s * 64 + q;
        float w = W[(size_t)k * NN + col];
        if (w != 0.0f) { idx[p] = (unsigned short)k; val[p] = w; ++p; }
    }
}

// rank columns by entry count (descending, stable) -> perm/iperm
__global__ __launch_bounds__(1024) void k_rank(const int* __restrict__ offs,
                                               int* __restrict__ perm, int* __restrict__ iperm) {
    __shared__ int sc[NN];
    int n = threadIdx.x;
    sc[n] = offs[n + 1] - offs[n];
    __syncthreads();
    int myc = sc[n];
    int r = 0;
    for (int m = 0; m < NN; ++m) {
        int cm = sc[m];
        r += (cm > myc || (cm == myc && m < n)) ? 1 : 0;
    }
    perm[r] = n;
    iperm[n] = r;
}

// Winp[i][r] = Win[i][perm[r]]  (rank-space input weights)
__global__ __launch_bounds__(256) void k_permwin(const float* __restrict__ Win, const int* __restrict__ perm,
                                                 float* __restrict__ Winp) {
    int idx = blockIdx.x * 256 + threadIdx.x;   // 65536 total
    int i = idx >> 10, r = idx & 1023;
    Winp[idx] = Win[(i << 10) + perm[r]];
}

// ---------- 4-choice bank-balanced address table ----------
// copies per phase: A +0 (bank x), B +4096 (x^g), C +8192 (x^(3g&31)),
// D +12288 (x^(5g&31)); x=r&31, g=r>>5. XOR maps bijective in-group;
// 1,3,5 invertible mod 32 so every cross-group A-collision is split.
__global__ __launch_bounds__(1024) void k_choice(const int* __restrict__ offs,
        const unsigned short* __restrict__ gidx, const int* __restrict__ perm,
        const int* __restrict__ iperm, unsigned short* __restrict__ eidx2) {
    __shared__ unsigned short rk[NN][NE];     // 57344 B
    __shared__ unsigned short scnt[NN];       // 2048 B
    __shared__ unsigned short ctr[448][32];   // 28672 B
    int tid = threadIdx.x;
    {
        int r = tid;
        int c = perm[r];
        int o0 = offs[c];
        int cn = offs[c + 1] - o0;
        if (cn > NE) cn = NE;
        scnt[r] = (unsigned short)cn;
        for (int j = 0; j < cn; ++j) rk[r][j] = (unsigned short)iperm[(int)gidx[o0 + j]];
    }
    __syncthreads();
    if (tid < 448) {
        int w = tid / NE, j = tid % NE;
        for (int b = 0; b < 32; ++b) ctr[tid][b] = 0;
        int first_addr = -1;
        for (int l = 0; l < 64; ++l) {
            int r = 64 * w + l;
            if (j < (int)scnt[r]) {
                int rr = (int)rk[r][j];
                int x = rr & 31, g = rr >> 5;
                int bk[4];
                bk[0] = x;
                bk[1] = x ^ (g & 31);
                bk[2] = x ^ ((3 * g) & 31);
                bk[3] = x ^ ((5 * g) & 31);
                int best = 0, bestload = (int)ctr[tid][bk[0]];
#pragma unroll
                for (int q = 1; q < 4; ++q) {
                    int ld = (int)ctr[tid][bk[q]];
                    if (ld < bestload) { bestload = ld; best = q; }
                }
                ctr[tid][bk[best]]++;
                int addr = best * 4096 + (((rr & ~31) | bk[best]) << 2);
                if (best == 0) addr = rr << 2;   // copy A keeps identity layout
                eidx2[j * NN + r] = (unsigned short)addr;
                if (first_addr < 0) first_addr = addr;
            }
        }
        unsigned short pad = (unsigned short)(first_addr < 0 ? 0 : first_addr);
        for (int l = 0; l < 64; ++l) {
            int r = 64 * w + l;
            if (j >= (int)scnt[r]) eidx2[j * NN + r] = pad;
        }
    }
}

// ---------- input projection: U[t][b][r] = sum_i In[b][i][t] * Winp[i][r], fp32 ----------
__global__ __launch_bounds__(256) void k_uproj3(const float* __restrict__ In, const float* __restrict__ Winp,
                                                float* __restrict__ U, int t0c, int nblk) {
    int b  = blockIdx.x / nblk;
    int tq = blockIdx.x % nblk;
    int t0 = t0c + tq * 32;
    __shared__ float s[32][NI + 1];
    int tid = threadIdx.x;
    {
        int i = tid >> 2, g = tid & 3;
        const float* ip = In + ((size_t)b * NI + i) * TT + t0 + g * 8;
        float4 v0 = *(const float4*)(ip);
        float4 v1 = *(const float4*)(ip + 4);
        s[g * 8 + 0][i] = v0.x; s[g * 8 + 1][i] = v0.y;
        s[g * 8 + 2][i] = v0.z; s[g * 8 + 3][i] = v0.w;
        s[g * 8 + 4][i] = v1.x; s[g * 8 + 5][i] = v1.y;
        s[g * 8 + 6][i] = v1.z; s[g * 8 + 7][i] = v1.w;
    }
    __syncthreads();
    const float4* W4 = (const float4*)Winp;
    float4* U4 = (float4*)U;
    for (int th = 0; th < 2; ++th) {
        float4 acc[16];
#pragma unroll
        for (int t = 0; t < 16; ++t) acc[t] = make_float4(0.f, 0.f, 0.f, 0.f);
        for (int i = 0; i < NI; ++i) {
            float4 w = W4[(size_t)i * 256 + tid];
#pragma unroll
            for (int t = 0; t < 16; ++t) {
                float sv = s[th * 16 + t][i];
                acc[t].x = fmaf(w.x, sv, acc[t].x);
                acc[t].y = fmaf(w.y, sv, acc[t].y);
                acc[t].z = fmaf(w.z, sv, acc[t].z);
                acc[t].w = fmaf(w.w, sv, acc[t].w);
            }
        }
#pragma unroll
        for (int t = 0; t < 16; ++t)
            U4[((size_t)(tq * 32 + th * 16 + t) * BB + b) * 256 + tid] = acc[t];
    }
}

// ---------- recurrence ----------
__device__ __forceinline__ float fast_tanh(float z) {
    float a = fabsf(z) * 2.885390082f;       // 2*log2(e)
    a = fminf(a, 60.0f);
    float e = __builtin_amdgcn_exp2f(a);     // e^{2|z|}
    float r = 1.0f - __fdividef(2.0f, e + 1.0f);
    return z < 0.0f ? -r : r;
}

#define L28(M) \
  M(0) M(1) M(2) M(3) M(4) M(5) M(6) M(7) M(8) M(9) M(10) M(11) M(12) M(13) \
  M(14) M(15) M(16) M(17) M(18) M(19) M(20) M(21) M(22) M(23) M(24) M(25) M(26) M(27)

#define DW(i)  float w##i; int a##i;
#define IW(i)  { a##i = (int)eidx2[(i) * NN + n]; \
                 w##i = (cnt > i) ? gval[o0 + i] : 0.0f; }

#define PIN_ALL \
  asm volatile("" : "+v"(w0),"+v"(w1),"+v"(w2),"+v"(w3),"+v"(w4),"+v"(w5),"+v"(w6),"+v"(w7)); \
  asm volatile("" : "+v"(w8),"+v"(w9),"+v"(w10),"+v"(w11),"+v"(w12),"+v"(w13),"+v"(w14),"+v"(w15)); \
  asm volatile("" : "+v"(w16),"+v"(w17),"+v"(w18),"+v"(w19),"+v"(w20),"+v"(w21),"+v"(w22),"+v"(w23)); \
  asm volatile("" : "+v"(w24),"+v"(w25),"+v"(w26),"+v"(w27)); \
  asm volatile("" : "+v"(a0),"+v"(a1),"+v"(a2),"+v"(a3),"+v"(a4),"+v"(a5),"+v"(a6),"+v"(a7)); \
  asm volatile("" : "+v"(a8),"+v"(a9),"+v"(a10),"+v"(a11),"+v"(a12),"+v"(a13),"+v"(a14),"+v"(a15)); \
  asm volatile("" : "+v"(a16),"+v"(a17),"+v"(a18),"+v"(a19),"+v"(a20),"+v"(a21),"+v"(a22),"+v"(a23)); \
  asm volatile("" : "+v"(a24),"+v"(a25),"+v"(a26),"+v"(a27));

// 2-entry guarded gather group (finer padding granularity than per-4)
#define GRP2(J, i0, i1) \
  if ((J) < wmax) { \
    float q0 = *(const float*)(xp + a##i0); \
    float q1 = *(const float*)(xp + a##i1); \
    z0 = fmaf(w##i0, q0, z0); z1 = fmaf(w##i1, q1, z1); \
  }

#define GATHER_ALL \
  GRP2(0, 0,1)    GRP2(2, 2,3)    GRP2(4, 4,5)    GRP2(6, 6,7) \
  GRP2(8, 8,9)    GRP2(10, 10,11) GRP2(12, 12,13) GRP2(14, 14,15) \
  GRP2(16, 16,17) GRP2(18, 18,19) GRP2(20, 20,21) GRP2(22, 22,23) \
  GRP2(24, 24,25) GRP2(26, 26,27)

// PH in {0, 16384}; each phase holds copies A/B/C/D at +0/+4096/+8192/+12288
#define STEP(PH, XDST) { \
    float u = unx; \
    int tn = t + 1; tn = (tn < Tc) ? tn : (Tc - 1); \
    unx = Ub[(size_t)tn * ustep]; \
    const char* xp = xb + (PH); \
    float z0 = u, z1 = 0.f; \
    GATHER_ALL \
    x = 0.5f * x + 0.5f * fast_tanh(z0 + z1); \
    XDST = x; \
    float* wb = (float*)(xb + ((PH) ^ 16384)); \
    wb[n] = x; \
    wb[NN + nB] = x; \
    wb[2 * NN + nC] = x; \
    wb[3 * NN + nD] = x; \
    __syncthreads(); \
    ++t; \
}

__global__ __launch_bounds__(1024, 4)
void k_step(const float* __restrict__ U,
            const int* __restrict__ offs, const unsigned short* __restrict__ eidx2,
            const float* __restrict__ gval, const int* __restrict__ perm,
            float* __restrict__ out, float* __restrict__ xstate, int t0, int Tc) {
    __shared__ float xbuf[2][4][NN];         // 32 KB: [phase][copy][rank]
    int b = blockIdx.x, n = threadIdx.x;
    int c = perm[n];                         // this thread's column (rank-sorted)
    int gn = n >> 5;
    int nB = (n & ~31) | ((n & 31) ^ (gn & 31));
    int nC = (n & ~31) | ((n & 31) ^ ((3 * gn) & 31));
    int nD = (n & ~31) | ((n & 31) ^ ((5 * gn) & 31));

    int o0 = offs[c];
    int cnt = offs[c + 1] - o0;
    L28(DW)
    L28(IW)
    PIN_ALL

    int wmax = cnt;
#pragma unroll
    for (int d = 1; d < 64; d <<= 1) {
        int o = __shfl_xor(wmax, d);
        wmax = wmax > o ? wmax : o;
    }
    wmax = __builtin_amdgcn_readfirstlane(wmax);

    float x = (t0 == 0) ? 0.0f : xstate[((size_t)b << 10) + n];
    xbuf[0][0][n] = x;
    xbuf[0][1][nB] = x;
    xbuf[0][2][nC] = x;
    xbuf[0][3][nD] = x;
    __syncthreads();

    char* xb = (char*)&xbuf[0][0][0];
    const float* Ub = U + (size_t)b * NN + n;
    const size_t ustep = (size_t)BB * NN;
    float unx = Ub[0];

    for (int tb = 0; tb < Tc; tb += TH) {
        PIN_ALL
        int t = tb;
        float y0, y1, y2, y3, y4, y5, y6, y7, y8, y9, y10, y11, y12, y13, y14, y15;
        STEP(0,     y0)
        STEP(16384, y1)
        STEP(0,     y2)
        STEP(16384, y3)
        STEP(0,     y4)
        STEP(16384, y5)
        STEP(0,     y6)
        STEP(16384, y7)
        STEP(0,     y8)
        STEP(16384, y9)
        STEP(0,     y10)
        STEP(16384, y11)
        STEP(0,     y12)
        STEP(16384, y13)
        STEP(0,     y14)
        STEP(16384, y15)
        float4* op = (float4*)(out + ((size_t)b * NN + c) * TT + (size_t)(t0 + tb));
        op[0] = make_float4(y0,  y1,  y2,  y3);
        op[1] = make_float4(y4,  y5,  y6,  y7);
        op[2] = make_float4(y8,  y9,  y10, y11);
        op[3] = make_float4(y12, y13, y14, y15);
    }
    if (Tc < TT) xstate[((size_t)b << 10) + n] = x;
}

extern "C" void kernel_launch(void* const* d_in, const int* in_sizes, int n_in,
                              void* d_out, int out_size, void* d_ws, size_t ws_size,
                              hipStream_t stream) {
    const float* In  = (const float*)d_in[0];
    const float* W   = (const float*)d_in[1];
    const float* Win = (const float*)d_in[2];
    float* out = (float*)d_out;
    char* ws = (char*)d_ws;
    int* offs           = (int*)(ws + WS_OFFS);
    int* cnt            = (int*)(ws + WS_CNT);
    unsigned short* idx = (unsigned short*)(ws + WS_IDX);
    float* val          = (float*)(ws + WS_VAL);
    int* perm           = (int*)(ws + WS_PERM);
    int* iperm          = (int*)(ws + WS_IPERM);
    float* xstate       = (float*)(ws + WS_XSTATE);
    float* Winp         = (float*)(ws + WS_WINP);
    unsigned short* eidx2 = (unsigned short*)(ws + WS_EIDX2);
    int* cnt16          = (int*)(ws + WS_CNT16);
    int* off16          = (int*)(ws + WS_OFF16);
    float* U            = (float*)(ws + WS_U);

    // biggest fp32 U chunk that fits in ws
    int Tc = 32;
    const int cands[5] = {512, 256, 128, 64, 32};
    for (int i = 0; i < 5; ++i) {
        if ((size_t)WS_U + (size_t)cands[i] * BB * NN * 4 <= ws_size) { Tc = cands[i]; break; }
    }

    k_count16<<<256, 64, 0, stream>>>(W, cnt16);
    k_sum16<<<1, 1024, 0, stream>>>(cnt16, cnt);
    k_scan<<<1, 1024, 0, stream>>>(cnt, offs);
    k_off16<<<1, 1024, 0, stream>>>(offs, cnt16, off16);
    k_fill16<<<256, 64, 0, stream>>>(W, off16, idx, val);
    k_rank<<<1, 1024, 0, stream>>>(offs, perm, iperm);
    k_permwin<<<256, 256, 0, stream>>>(Win, perm, Winp);
    k_choice<<<1, 1024, 0, stream>>>(offs, idx, perm, iperm, eidx2);

    for (int t0 = 0; t0 < TT; t0 += Tc) {
        int nblk = Tc / 32;
        k_uproj3<<<BB * nblk, 256, 0, stream>>>(In, Winp, U, t0, nblk);
        k_step<<<BB, 1024, 0, stream>>>(U, offs, eidx2, val, perm, out, xstate, t0, Tc);
    }
}

// Round 14
// 656.232 us; speedup vs baseline: 1.0580x; 1.0580x over previous
//
#include <hip/hip_runtime.h>
#include <hip/hip_fp16.h>
#include <cstdint>
#include <cstddef>

#define BB 128
#define NN 1024
#define NI 64
#define TT 512
#define MAXNNZ 16384
#define NE 28
#define TH 16

// ws layout (bytes)
#define WS_OFFS   0u         // int[1025]
#define WS_IDX    16384u     // u16[MAXNNZ]
#define WS_VAL    65536u     // f32[MAXNNZ]
#define WS_PERM   131072u    // int[1024]
#define WS_IPERM  135168u    // int[1024]
#define WS_XSTATE 139264u    // f32[BB*NN]
#define WS_WINP   663552u    // f32[NI*NN]
#define WS_EIDX2  925696u    // u16[NE*NN] = 57344
#define WS_CNT16  983040u    // int[1024*16] = 65536
#define WS_OFF16  1048576u   // int[1024*16] = 65536
#define WS_U      1114112u   // fp16 U chunk [Tc][BB][NN]

// ---------- sparse build (parallel, deterministic k-order) ----------
__global__ __launch_bounds__(64) void k_count16(const float* __restrict__ W, int* __restrict__ cnt16) {
    int bc = blockIdx.x;
    int s = bc & 15, g = bc >> 4;
    int col = g * 64 + threadIdx.x;
    int c = 0;
    for (int q = 0; q < 64; ++q) {
        int k = s * 64 + q;
        c += (W[(size_t)k * NN + col] != 0.0f) ? 1 : 0;
    }
    cnt16[col * 16 + s] = c;
}

// fused: per-col sum, block scan -> offs, per-slab offsets -> off16
__global__ __launch_bounds__(1024) void k_scan3(const int* __restrict__ cnt16, int* __restrict__ offs,
                                                int* __restrict__ off16) {
    __shared__ int s[NN];
    int tid = threadIdx.x;
    int t = 0;
#pragma unroll
    for (int q = 0; q < 16; ++q) t += cnt16[tid * 16 + q];
    s[tid] = t;
    __syncthreads();
    for (int d = 1; d < NN; d <<= 1) {
        int v = (tid >= d) ? s[tid - d] : 0;
        __syncthreads();
        s[tid] += v;
        __syncthreads();
    }
    int incl = s[tid];
    offs[tid + 1] = (incl < MAXNNZ) ? incl : MAXNNZ;
    if (tid == 0) offs[0] = 0;
    int base = incl - t;                      // exclusive prefix
#pragma unroll
    for (int q = 0; q < 16; ++q) {
        off16[tid * 16 + q] = base;
        base += cnt16[tid * 16 + q];
    }
}

__global__ __launch_bounds__(64) void k_fill16(const float* __restrict__ W, const int* __restrict__ off16,
                                               unsigned short* __restrict__ idx, float* __restrict__ val) {
    int bc = blockIdx.x;
    int s = bc & 15, g = bc >> 4;
    int col = g * 64 + threadIdx.x;
    int p = off16[col * 16 + s];
    for (int q = 0; q < 64; ++q) {
        int k = s * 64 + q;
        float w = W[(size_t)k * NN + col];
        if (w != 0.0f) { idx[p] = (unsigned short)k; val[p] = w; ++p; }
    }
}

// fused rank (count-sort, stable) + 2-choice bank-balanced address table
__global__ __launch_bounds__(1024) void k_rankchoice(const int* __restrict__ offs,
        const unsigned short* __restrict__ gidx, int* __restrict__ perm, int* __restrict__ iperm,
        unsigned short* __restrict__ eidx2) {
    __shared__ int sc[NN];                    // 4 KB
    __shared__ unsigned short rk[NN][NE];     // 57344 B
    __shared__ unsigned short scnt[NN];       // 2048 B
    __shared__ unsigned short ctr[448][32];   // 28672 B
    int n = threadIdx.x;
    sc[n] = offs[n + 1] - offs[n];
    __syncthreads();
    int myc = sc[n];
    int r = 0;
    for (int m = 0; m < NN; ++m) {
        int cm = sc[m];
        r += (cm > myc || (cm == myc && m < n)) ? 1 : 0;
    }
    perm[r] = n;
    iperm[n] = r;
    __syncthreads();                          // global writes visible block-wide
    {
        int rr = n;
        int c = perm[rr];
        int o0 = offs[c];
        int cn = offs[c + 1] - o0;
        if (cn > NE) cn = NE;
        scnt[rr] = (unsigned short)cn;
        for (int j = 0; j < cn; ++j) rk[rr][j] = (unsigned short)iperm[(int)gidx[o0 + j]];
    }
    __syncthreads();
    int tid = n;
    if (tid < 448) {
        int w = tid / NE, j = tid % NE;
        for (int b = 0; b < 32; ++b) ctr[tid][b] = 0;
        int first_addr = -1;
        for (int l = 0; l < 64; ++l) {
            int rr = 64 * w + l;
            if (j < (int)scnt[rr]) {
                int rv = (int)rk[rr][j];
                int bA = rv & 31;
                int bB = (rv ^ (rv >> 5)) & 31;
                int addr;
                if (ctr[tid][bA] <= ctr[tid][bB]) { addr = rv << 2; ctr[tid][bA]++; }
                else { addr = 4096 + (((rv & ~31) | bB) << 2); ctr[tid][bB]++; }
                eidx2[j * NN + rr] = (unsigned short)addr;
                if (first_addr < 0) first_addr = addr;
            }
        }
        unsigned short pad = (unsigned short)(first_addr < 0 ? 0 : first_addr);
        for (int l = 0; l < 64; ++l) {
            int rr = 64 * w + l;
            if (j >= (int)scnt[rr]) eidx2[j * NN + rr] = pad;
        }
    }
}

// Winp[i][r] = Win[i][perm[r]]  (rank-space input weights)
__global__ __launch_bounds__(256) void k_permwin(const float* __restrict__ Win, const int* __restrict__ perm,
                                                 float* __restrict__ Winp) {
    int idx = blockIdx.x * 256 + threadIdx.x;   // 65536 total
    int i = idx >> 10, r = idx & 1023;
    Winp[idx] = Win[(i << 10) + perm[r]];
}

// ---------- input projection: U[t][b][r] = sum_i In[b][i][t] * Winp[i][r], fp16 ----------
__global__ __launch_bounds__(256) void k_uproj3(const float* __restrict__ In, const float* __restrict__ Winp,
                                                __half* __restrict__ U, int t0c, int nblk) {
    int b  = blockIdx.x / nblk;
    int tq = blockIdx.x % nblk;
    int t0 = t0c + tq * 32;
    __shared__ float s[32][NI + 1];
    int tid = threadIdx.x;
    {
        int i = tid >> 2, g = tid & 3;
        const float* ip = In + ((size_t)b * NI + i) * TT + t0 + g * 8;
        float4 v0 = *(const float4*)(ip);
        float4 v1 = *(const float4*)(ip + 4);
        s[g * 8 + 0][i] = v0.x; s[g * 8 + 1][i] = v0.y;
        s[g * 8 + 2][i] = v0.z; s[g * 8 + 3][i] = v0.w;
        s[g * 8 + 4][i] = v1.x; s[g * 8 + 5][i] = v1.y;
        s[g * 8 + 6][i] = v1.z; s[g * 8 + 7][i] = v1.w;
    }
    __syncthreads();
    const float4* W4 = (const float4*)Winp;
    uint2* U2 = (uint2*)U;
    for (int th = 0; th < 2; ++th) {
        float4 acc[16];
#pragma unroll
        for (int t = 0; t < 16; ++t) acc[t] = make_float4(0.f, 0.f, 0.f, 0.f);
        for (int i = 0; i < NI; ++i) {
            float4 w = W4[(size_t)i * 256 + tid];
#pragma unroll
            for (int t = 0; t < 16; ++t) {
                float sv = s[th * 16 + t][i];
                acc[t].x = fmaf(w.x, sv, acc[t].x);
                acc[t].y = fmaf(w.y, sv, acc[t].y);
                acc[t].z = fmaf(w.z, sv, acc[t].z);
                acc[t].w = fmaf(w.w, sv, acc[t].w);
            }
        }
#pragma unroll
        for (int t = 0; t < 16; ++t) {
            __half2 h01 = __floats2half2_rn(acc[t].x, acc[t].y);
            __half2 h23 = __floats2half2_rn(acc[t].z, acc[t].w);
            uint2 pk;
            pk.x = *(unsigned int*)&h01;
            pk.y = *(unsigned int*)&h23;
            U2[((size_t)(tq * 32 + th * 16 + t) * BB + b) * 256 + tid] = pk;
        }
    }
}

// ---------- recurrence ----------
__device__ __forceinline__ float fast_tanh(float z) {
    float a = fabsf(z) * 2.885390082f;       // 2*log2(e)
    a = fminf(a, 60.0f);
    float e = __builtin_amdgcn_exp2f(a);     // e^{2|z|}
    float r = 1.0f - __fdividef(2.0f, e + 1.0f);
    return z < 0.0f ? -r : r;
}

#define L28(M) \
  M(0) M(1) M(2) M(3) M(4) M(5) M(6) M(7) M(8) M(9) M(10) M(11) M(12) M(13) \
  M(14) M(15) M(16) M(17) M(18) M(19) M(20) M(21) M(22) M(23) M(24) M(25) M(26) M(27)

#define DW(i)  float w##i; int a##i;
#define IW(i)  { a##i = (int)eidx2[(i) * NN + n]; \
                 w##i = (cnt > i) ? gval[o0 + i] : 0.0f; }

#define PIN_ALL \
  asm volatile("" : "+v"(w0),"+v"(w1),"+v"(w2),"+v"(w3),"+v"(w4),"+v"(w5),"+v"(w6),"+v"(w7)); \
  asm volatile("" : "+v"(w8),"+v"(w9),"+v"(w10),"+v"(w11),"+v"(w12),"+v"(w13),"+v"(w14),"+v"(w15)); \
  asm volatile("" : "+v"(w16),"+v"(w17),"+v"(w18),"+v"(w19),"+v"(w20),"+v"(w21),"+v"(w22),"+v"(w23)); \
  asm volatile("" : "+v"(w24),"+v"(w25),"+v"(w26),"+v"(w27)); \
  asm volatile("" : "+v"(a0),"+v"(a1),"+v"(a2),"+v"(a3),"+v"(a4),"+v"(a5),"+v"(a6),"+v"(a7)); \
  asm volatile("" : "+v"(a8),"+v"(a9),"+v"(a10),"+v"(a11),"+v"(a12),"+v"(a13),"+v"(a14),"+v"(a15)); \
  asm volatile("" : "+v"(a16),"+v"(a17),"+v"(a18),"+v"(a19),"+v"(a20),"+v"(a21),"+v"(a22),"+v"(a23)); \
  asm volatile("" : "+v"(a24),"+v"(a25),"+v"(a26),"+v"(a27));

// 4-entry guarded gather group (wave-uniform guard, sorted => tight)
#define GRP(J, i0, i1, i2, i3) \
  if ((J) < wmax) { \
    float q0 = *(const float*)(xp + a##i0); \
    float q1 = *(const float*)(xp + a##i1); \
    float q2 = *(const float*)(xp + a##i2); \
    float q3 = *(const float*)(xp + a##i3); \
    z0 = fmaf(w##i0, q0, z0); z1 = fmaf(w##i1, q1, z1); \
    z2 = fmaf(w##i2, q2, z2); z3 = fmaf(w##i3, q3, z3); \
  }

#define GATHER_ALL \
  GRP(0, 0,1,2,3)      GRP(4, 4,5,6,7)      GRP(8, 8,9,10,11) \
  GRP(12, 12,13,14,15) GRP(16, 16,17,18,19) GRP(20, 20,21,22,23) \
  GRP(24, 24,25,26,27)

// PH in {0, 8192}; each phase holds copy A (+0) and copy B (+4096)
#define STEP(PH, XDST) { \
    float u = unx; \
    int tn = t + 1; tn = (tn < Tc) ? tn : (Tc - 1); \
    unx = (float)Ub[(size_t)tn * ustep]; \
    const char* xp = xb + (PH); \
    float z0 = u, z1 = 0.f, z2 = 0.f, z3 = 0.f; \
    GATHER_ALL \
    x = 0.5f * x + 0.5f * fast_tanh((z0 + z1) + (z2 + z3)); \
    XDST = x; \
    float* wb = (float*)(xb + ((PH) ^ 8192)); \
    wb[n] = x; \
    wb[NN + nB] = x; \
    __syncthreads(); \
    ++t; \
}

__global__ __launch_bounds__(1024, 4)
void k_step(const __half* __restrict__ U,
            const int* __restrict__ offs, const unsigned short* __restrict__ eidx2,
            const float* __restrict__ gval, const int* __restrict__ perm,
            float* __restrict__ out, float* __restrict__ xstate, int t0, int Tc) {
    __shared__ float xbuf[2][2][NN];         // 16 KB: [phase][copy][rank]
    int b = blockIdx.x, n = threadIdx.x;
    int c = perm[n];                         // this thread's column (rank-sorted)
    int nB = (n & ~31) | ((n ^ (n >> 5)) & 31);

    int o0 = offs[c];
    int cnt = offs[c + 1] - o0;
    L28(DW)
    L28(IW)
    PIN_ALL

    int wmax = cnt;
#pragma unroll
    for (int d = 1; d < 64; d <<= 1) {
        int o = __shfl_xor(wmax, d);
        wmax = wmax > o ? wmax : o;
    }
    wmax = __builtin_amdgcn_readfirstlane(wmax);

    float x = (t0 == 0) ? 0.0f : xstate[((size_t)b << 10) + n];
    xbuf[0][0][n] = x;
    xbuf[0][1][nB] = x;
    __syncthreads();

    char* xb = (char*)&xbuf[0][0][0];
    const __half* Ub = U + (size_t)b * NN + n;
    const size_t ustep = (size_t)BB * NN;
    float unx = (float)Ub[0];

    for (int tb = 0; tb < Tc; tb += TH) {
        PIN_ALL
        int t = tb;
        float y0, y1, y2, y3, y4, y5, y6, y7, y8, y9, y10, y11, y12, y13, y14, y15;
        STEP(0,    y0)
        STEP(8192, y1)
        STEP(0,    y2)
        STEP(8192, y3)
        STEP(0,    y4)
        STEP(8192, y5)
        STEP(0,    y6)
        STEP(8192, y7)
        STEP(0,    y8)
        STEP(8192, y9)
        STEP(0,    y10)
        STEP(8192, y11)
        STEP(0,    y12)
        STEP(8192, y13)
        STEP(0,    y14)
        STEP(8192, y15)
        float4* op = (float4*)(out + ((size_t)b * NN + c) * TT + (size_t)(t0 + tb));
        op[0] = make_float4(y0,  y1,  y2,  y3);
        op[1] = make_float4(y4,  y5,  y6,  y7);
        op[2] = make_float4(y8,  y9,  y10, y11);
        op[3] = make_float4(y12, y13, y14, y15);
    }
    if (Tc < TT) xstate[((size_t)b << 10) + n] = x;
}

extern "C" void kernel_launch(void* const* d_in, const int* in_sizes, int n_in,
                              void* d_out, int out_size, void* d_ws, size_t ws_size,
                              hipStream_t stream) {
    const float* In  = (const float*)d_in[0];
    const float* W   = (const float*)d_in[1];
    const float* Win = (const float*)d_in[2];
    float* out = (float*)d_out;
    char* ws = (char*)d_ws;
    int* offs           = (int*)(ws + WS_OFFS);
    unsigned short* idx = (unsigned short*)(ws + WS_IDX);
    float* val          = (float*)(ws + WS_VAL);
    int* perm           = (int*)(ws + WS_PERM);
    int* iperm          = (int*)(ws + WS_IPERM);
    float* xstate       = (float*)(ws + WS_XSTATE);
    float* Winp         = (float*)(ws + WS_WINP);
    unsigned short* eidx2 = (unsigned short*)(ws + WS_EIDX2);
    int* cnt16          = (int*)(ws + WS_CNT16);
    int* off16          = (int*)(ws + WS_OFF16);
    __half* U           = (__half*)(ws + WS_U);

    // biggest fp16 U chunk that fits in ws
    int Tc = 32;
    const int cands[5] = {512, 256, 128, 64, 32};
    for (int i = 0; i < 5; ++i) {
        if ((size_t)WS_U + (size_t)cands[i] * BB * NN * 2 <= ws_size) { Tc = cands[i]; break; }
    }

    k_count16<<<256, 64, 0, stream>>>(W, cnt16);
    k_scan3<<<1, 1024, 0, stream>>>(cnt16, offs, off16);
    k_fill16<<<256, 64, 0, stream>>>(W, off16, idx, val);
    k_rankchoice<<<1, 1024, 0, stream>>>(offs, idx, perm, iperm, eidx2);
    k_permwin<<<256, 256, 0, stream>>>(Win, perm, Winp);

    for (int t0 = 0; t0 < TT; t0 += Tc) {
        int nblk = Tc / 32;
        k_uproj3<<<BB * nblk, 256, 0, stream>>>(In, Winp, U, t0, nblk);
        k_step<<<BB, 1024, 0, stream>>>(U, offs, eidx2, val, perm, out, xstate, t0, Tc);
    }
}